// Round 4
// baseline (259.912 us; speedup 1.0000x reference)
//
#include <hip/hip_runtime.h>

// compute_threebody_indices for MatterSim on gfx950 — v5 (3 free-running kernels).
//
// Outputs (int32, concatenated flat in d_out):
//   [0, 2T)                       bond_indices [T,2]  (pairs of ORIGINAL bond ids)
//   [2T, 2T+n_bond)               n_triple_ij
//   [.., +n_atom)                 n_triple_i
//   [.., +n_struct)               n_triple_s
//
// v5 changes vs v4 (256.6 us; v2 best = 244.1):
//  - kA reverted to the proven v2 per-bond ballot skeleton (v4's quad rewrite
//    multiplied atomics ~5x and regressed ~25us), then upgraded: TRUE-tail
//    detection (src[i+1] differs) lets the unique tail thread count the whole
//    run (backward global walk for the rare wave-spanning run) and write deg
//    with a PLAIN STORE — no atomics at all.
//  - k0 deleted: gap (bondless) atoms' wstart/wend/deg are zeroed by run-head
//    threads (gaps are ~nonexistent for this data); kA zeroes the kBC `done`
//    counter (safe: stream-ordered before kBC).
//  - kD caches kept-ballots in registers; the n_triple_ij pass re-reads no len.
//  - kBC byte-identical logic to v4 (hardware-proven correct).

#define CUTOFF 0.8f
#define NATOM_C 100000
#define MAXD 256   // max kept bonds per atom; actual max ~45 (Poisson mean ~16)

// ---- KA: segment bounds + kept-degree (plain stores, no atomics) ----
// Sorted src => runs contiguous. head/tail from neighbor compares (shuffles +
// edge loads). The tail thread counts kept bonds of the ENTIRE run: in-wave
// part via masked ballot popcount; if the run extends before the wave, a
// backward global walk (<= run length, L1/L2-hot) adds the rest. Run-head
// threads zero the (empty) gap atoms so no init kernel is needed.
__global__ void kA_bounds_deg(const int* __restrict__ src, const float* __restrict__ len,
                              int* __restrict__ wstart, int* __restrict__ wend,
                              int* __restrict__ deg, int* __restrict__ done,
                              int n_bond, int n_atom) {
    int i = blockIdx.x * blockDim.x + threadIdx.x;
    if (i == 0) *done = 0;               // consumed by kBC (stream-ordered after)
    int lane = threadIdx.x & 63;
    bool valid = i < n_bond;
    int a = -1; bool kept = false;
    if (valid) { a = src[i]; kept = (len[i] <= CUTOFF); }

    // neighbor atoms (all lanes participate in shuffles; edges load global)
    int ap = __shfl_up(a, 1);
    if (lane == 0) ap = (valid && i > 0) ? src[i - 1] : -1;
    int an = __shfl_down(a, 1);
    if (lane == 63) an = (valid && i + 1 < n_bond) ? src[i + 1] : -2;

    bool head = valid && (i == 0 || ap != a);
    bool tail = valid && (i == n_bond - 1 || an != a);

    unsigned long long keptB = __ballot(kept);
    unsigned long long headB = __ballot(head);

    if (head) {
        wstart[a] = i;
        // zero bondless atoms in the gap (prev_atom, a) — ~never taken here
        int p = (i == 0) ? -1 : ap;
        for (int g = p + 1; g < a; ++g) { wstart[g] = 0; wend[g] = 0; deg[g] = 0; }
    }
    if (tail) {
        wend[a] = i + 1;
        if (i == n_bond - 1)             // trailing gap at the very end
            for (int g = a + 1; g < n_atom; ++g) { wstart[g] = 0; wend[g] = 0; deg[g] = 0; }

        // count kept bonds of the whole run
        unsigned long long belowInc = (lane == 63) ? ~0ull : ((2ull << lane) - 1ull);
        unsigned long long h = headB & belowInc;
        int cnt;
        if (h) {                          // run starts within this wave
            int runStartLane = 63 - __clzll(h);
            unsigned long long runMask = belowInc & ~((1ull << runStartLane) - 1ull);
            cnt = __popcll(keptB & runMask);
        } else {                          // run extends before the wave: walk back
            cnt = __popcll(keptB & belowInc);
            int wbase = i - lane;         // wave's first global index
            for (int j = wbase - 1; j >= 0; --j) {
                if (src[j] != a) break;
                if (len[j] <= CUTOFF) cnt++;
            }
        }
        deg[a] = cnt;                     // plain store: exactly one tail per run
    }
}

// ---- KBC: per-tile exclusive scan of d*(d-1) + n_triple_i out; the LAST
//           finishing block scans block sums in place and emits n_triple_s ----
__global__ void kBC_scan(const int* __restrict__ deg, int* __restrict__ out_i,
                         int* __restrict__ exsc, int* __restrict__ bsums,
                         int* __restrict__ done, const int* __restrict__ n_atoms_arr,
                         int* __restrict__ out_s,
                         int n_atom, int ntiles, int n_struct) {
    __shared__ int tmp[256];
    __shared__ int isLast;
    int t = threadIdx.x;
    int base = blockIdx.x * 1024 + t * 4;
    int v0 = 0, v1 = 0, v2 = 0, v3 = 0;
    if (base + 3 < n_atom) {
        int4 d4 = *(const int4*)(deg + base);
        v0 = d4.x * (d4.x - 1); v1 = d4.y * (d4.y - 1);
        v2 = d4.z * (d4.z - 1); v3 = d4.w * (d4.w - 1);
        *(int4*)(out_i + base) = make_int4(v0, v1, v2, v3);
    } else {
        if (base     < n_atom) { int d = deg[base];     v0 = d * (d - 1); out_i[base]     = v0; }
        if (base + 1 < n_atom) { int d = deg[base + 1]; v1 = d * (d - 1); out_i[base + 1] = v1; }
        if (base + 2 < n_atom) { int d = deg[base + 2]; v2 = d * (d - 1); out_i[base + 2] = v2; }
        if (base + 3 < n_atom) { int d = deg[base + 3]; v3 = d * (d - 1); out_i[base + 3] = v3; }
    }
    int s = v0 + v1 + v2 + v3;
    tmp[t] = s;
    __syncthreads();
    for (int off = 1; off < 256; off <<= 1) {
        int v = (t >= off) ? tmp[t - off] : 0;
        __syncthreads();
        tmp[t] += v;
        __syncthreads();
    }
    int excl = tmp[t] - s;                       // exclusive prefix within tile
    if (base     < n_atom) exsc[base]     = excl;
    if (base + 1 < n_atom) exsc[base + 1] = excl + v0;
    if (base + 2 < n_atom) exsc[base + 2] = excl + v0 + v1;
    if (base + 3 < n_atom) exsc[base + 3] = excl + v0 + v1 + v2;
    if (t == 255) bsums[blockIdx.x] = tmp[255];  // tile total
    __syncthreads();
    if (t == 0) {
        __threadfence();                         // publish exsc + bsums device-wide
        int old = __hip_atomic_fetch_add(done, 1, __ATOMIC_ACQ_REL,
                                         __HIP_MEMORY_SCOPE_AGENT);
        isLast = (old == (int)gridDim.x - 1);
    }
    __syncthreads();
    if (!isLast) return;

    // ---- last block: exclusive scan of bsums[0..ntiles) in place + n_triple_s ----
    int v = 0;
    if (t < ntiles)
        v = __hip_atomic_load(&bsums[t], __ATOMIC_RELAXED, __HIP_MEMORY_SCOPE_AGENT);
    tmp[t] = v;
    __syncthreads();
    for (int off = 1; off < 256; off <<= 1) {
        int x = (t >= off) ? tmp[t - off] : 0;
        __syncthreads();
        tmp[t] += x;
        __syncthreads();
    }
    if (t < ntiles) bsums[t] = tmp[t] - v;       // exclusive scanned tile offsets
    int total = tmp[255];
    __threadfence_block();
    __syncthreads();
    if (t == 0) {
        int off = 0, prevA = 0;
        for (int s2 = 0; s2 < n_struct; s2++) {
            off += n_atoms_arr[s2];
            int A;
            if (off >= n_atom) A = total;
            else A = __hip_atomic_load(&exsc[off], __ATOMIC_RELAXED,
                                       __HIP_MEMORY_SCOPE_AGENT) + bsums[off >> 10];
            out_s[s2] = A - prevA;
            prevA = A;
        }
    }
}

// ---- KD: wave-per-atom triple enumeration + n_triple_ij (4 atoms / block) ----
// Kept-ballots cached in registers (statically indexed — unrolled) so the
// n_triple_ij pass re-reads no len. Two consecutive triples per lane iteration
// as one int4 (16B-aligned: every tstart/base_row is even).
__global__ void kD_enum(const float* __restrict__ len, const int* __restrict__ wstart,
                        const int* __restrict__ wend, const int* __restrict__ exsc,
                        const int* __restrict__ bsums,
                        int4* __restrict__ out4, int* __restrict__ out_ij,
                        int n_atom) {
    __shared__ int keptIds[4 * MAXD];
    int wave = threadIdx.x >> 6;
    int lane = threadIdx.x & 63;
    int a = blockIdx.x * 4 + wave;
    int* my = &keptIds[wave * MAXD];
    if (a >= n_atom) return;
    int s = wstart[a], e = wend[a];
    int d = 0;
    unsigned long long bal[4] = {0ull, 0ull, 0ull, 0ull};
    // order-preserving compaction of kept ORIGINAL bond ids into LDS
#pragma unroll
    for (int it = 0; it < 4; ++it) {             // static indices -> registers
        int base = s + it * 64;
        if (base < e) {
            int idx = base + lane;
            bool m = (idx < e) && (len[idx] <= CUTOFF);
            unsigned long long b = __ballot(m);
            bal[it] = b;
            int pos = d + __popcll(b & ((1ull << lane) - 1ull));
            if (m && pos < MAXD) my[pos] = idx;
            d += __popcll(b);
        }
    }
    for (int base = s + 256; base < e; base += 64) {   // cold path (never here)
        int idx = base + lane;
        bool m = (idx < e) && (len[idx] <= CUTOFF);
        unsigned long long b = __ballot(m);
        int pos = d + __popcll(b & ((1ull << lane) - 1ull));
        if (m && pos < MAXD) my[pos] = idx;
        d += __popcll(b);
    }
    int dm1 = d - 1;
#pragma unroll
    for (int it = 0; it < 4; ++it) {
        int idx = s + it * 64 + lane;
        if (idx < e) out_ij[idx] = ((bal[it] >> lane) & 1ull) ? dm1 : 0;
    }
    for (int base = s + 256; base < e; base += 64) {   // cold path
        int idx = base + lane;
        if (idx < e) out_ij[idx] = (len[idx] <= CUTOFF) ? dm1 : 0;
    }
    if (d >= 2) {
        unsigned udm1 = (unsigned)dm1;
        unsigned nP = ((unsigned)(d * dm1)) >> 1;        // pairs of triples
        int b4 = (exsc[a] + bsums[a >> 10]) >> 1;        // tstart[a]/2, exact
        for (unsigned p = lane; p < nP; p += 64) {
            unsigned t0 = 2u * p;
            unsigned j  = t0 / udm1;                     // one div per PAIR
            unsigned kp = t0 - j * udm1;
            unsigned j1 = j, kp1 = kp + 1;
            if (kp1 == udm1) { j1++; kp1 = 0; }          // t0+1 rollover
            unsigned k0 = kp  + (kp  >= j  ? 1u : 0u);   // skip k == j
            unsigned k1 = kp1 + (kp1 >= j1 ? 1u : 0u);
            out4[b4 + p] = make_int4(my[j], my[k0], my[j1], my[k1]);
        }
    }
}

// ================================ launch ================================
extern "C" void kernel_launch(void* const* d_in, const int* in_sizes, int n_in,
                              void* d_out, int out_size, void* d_ws, size_t ws_size,
                              hipStream_t stream) {
    const int*   bond_src    = (const int*)d_in[0];
    const float* bond_len    = (const float*)d_in[1];
    const int*   n_atoms_arr = (const int*)d_in[2];
    int n_bond   = in_sizes[0];
    int n_struct = in_sizes[2];
    const int n_atom = NATOM_C;
    int T2 = out_size - n_bond - n_atom - n_struct;   // = 2*T

    int ntiles = (n_atom + 1023) / 1024;              // 98 (<= 256 required)

    // workspace (ints): wstart | wend | deg | exsc[n_atom] | bsums[ntiles] | done
    int* ws     = (int*)d_ws;
    int* wstart = ws;
    int* wend   = ws + n_atom;
    int* deg    = ws + 2 * n_atom;
    int* exsc   = ws + 3 * n_atom;
    int* bsums  = exsc + n_atom;
    int* done   = bsums + ntiles;

    int*  out       = (int*)d_out;
    int4* out_pairs = (int4*)out;          // [T/2] rows of 2 triples, 16B-aligned
    int*  out_ij    = out + T2;
    int*  out_i     = out_ij + n_bond;
    int*  out_s     = out_i + n_atom;

    kA_bounds_deg<<<(n_bond + 255) / 256, 256, 0, stream>>>(bond_src, bond_len, wstart, wend,
                                                            deg, done, n_bond, n_atom);
    kBC_scan     <<<ntiles, 256, 0, stream>>>(deg, out_i, exsc, bsums, done, n_atoms_arr,
                                              out_s, n_atom, ntiles, n_struct);
    kD_enum      <<<(n_atom + 3) / 4, 256, 0, stream>>>(bond_len, wstart, wend, exsc, bsums,
                                                        out_pairs, out_ij, n_atom);
}

// Round 6
// 256.279 us; speedup vs baseline: 1.0142x; 1.0142x over previous
//
#include <hip/hip_runtime.h>

// compute_threebody_indices for MatterSim on gfx950 — v6b.
// Structure = v2 exactly (5 free-running kernels, best measured 244.1 us).
// v3 (cooperative mega) = 628, v4 (kBC fusion + quad kA) = 256.6,
// v5 (kBC fusion + no-atomic kA) = 259.9 — all reverted.
//
// v6 single-scope change (inside kD only, the dominant kernel):
//  - nontemporal stores for the 205MB pair stream + 8MB n_triple_ij (write-
//    once data; stop evicting the 32MB L2 that kD wants hot for len/tstart).
//    v6b: NT store via clang ext_vector_type (HIP's int4 class is rejected by
//    __builtin_nontemporal_store).
//  - kept-ballots cached in registers: n_triple_ij pass re-reads no len.
//  - kB keeps v4's proven int4 deg load (confined, trivial).
//
// Outputs (int32, concatenated flat in d_out):
//   [0, 2T)                       bond_indices [T,2]  (pairs of ORIGINAL bond ids)
//   [2T, 2T+n_bond)               n_triple_ij
//   [.., +n_atom)                 n_triple_i
//   [.., +n_struct)               n_triple_s

#define CUTOFF 0.8f
#define NATOM_C 100000
#define MAXD 256   // max kept bonds per atom; actual max ~45 (Poisson mean ~16)

typedef int v4i __attribute__((ext_vector_type(4)));

// ---- K0: init per-atom ranges to empty + zero degree accumulators ----
__global__ void k0_init(int* wstart, int* wend, int* deg, int n_atom) {
    int i = blockIdx.x * blockDim.x + threadIdx.x;
    if (i < n_atom) { wstart[i] = 0; wend[i] = 0; deg[i] = 0; }
}

// ---- KA: segment boundaries + kept-degree count on sorted bond_src ----
// Runs of equal src are contiguous; within a wave, count kept bonds per run
// with popcount over the ballot and do ONE atomicAdd per run-tail. Partial
// runs at wave edges just contribute partial counts (atomics sum).
__global__ void kA_bounds_deg(const int* __restrict__ src, const float* __restrict__ len,
                              int* __restrict__ wstart, int* __restrict__ wend,
                              int* __restrict__ deg, int n_bond) {
    int i = blockIdx.x * blockDim.x + threadIdx.x;
    int lane = threadIdx.x & 63;
    bool valid = i < n_bond;
    int a = -1;
    bool kept = false;
    if (valid) {
        a = src[i];
        if (i == 0 || src[i - 1] != a) wstart[a] = i;
        if (i == n_bond - 1 || src[i + 1] != a) wend[a] = i + 1;
        kept = (len[i] <= CUTOFF);
    }
    unsigned long long keptB = __ballot(kept);
    int ap = __shfl_up(a, 1);
    bool head = (lane == 0) || (ap != a);
    unsigned long long headB = __ballot(head);
    unsigned long long nextHeads = (headB >> 1) >> lane;   // heads strictly above
    bool tail = (lane == 63) || ((nextHeads & 1ull) != 0ull);
    if (tail && valid) {
        unsigned long long below = (lane == 63) ? ~0ull : ((2ull << lane) - 1ull);
        int runStart = 63 - __clzll(headB & below);        // headB bit0 always set
        unsigned long long runMask = below & ~((1ull << runStart) - 1ull);
        int cnt = __popcll(keptB & runMask);
        if (cnt) atomicAdd(&deg[a], cnt);
    }
}

// ---- KB: per-block (1024-elem chunk) exclusive scan of d*(d-1);
//          also writes n_triple_i output. Block totals to bsums. ----
__global__ void kB_scan(const int* __restrict__ deg, int* __restrict__ out_i,
                        int* __restrict__ exsc, int* __restrict__ bsums, int n) {
    __shared__ int tmp[256];
    int t = threadIdx.x;
    int base = blockIdx.x * 1024 + t * 4;
    int v0 = 0, v1 = 0, v2 = 0, v3 = 0;
    if (base + 3 < n) {
        int4 d4 = *(const int4*)(deg + base);
        v0 = d4.x * (d4.x - 1); v1 = d4.y * (d4.y - 1);
        v2 = d4.z * (d4.z - 1); v3 = d4.w * (d4.w - 1);
        *(int4*)(out_i + base) = make_int4(v0, v1, v2, v3);
    } else {
        if (base     < n) { int d = deg[base];     v0 = d * (d - 1); out_i[base]     = v0; }
        if (base + 1 < n) { int d = deg[base + 1]; v1 = d * (d - 1); out_i[base + 1] = v1; }
        if (base + 2 < n) { int d = deg[base + 2]; v2 = d * (d - 1); out_i[base + 2] = v2; }
        if (base + 3 < n) { int d = deg[base + 3]; v3 = d * (d - 1); out_i[base + 3] = v3; }
    }
    int s = v0 + v1 + v2 + v3;
    tmp[t] = s;
    __syncthreads();
    for (int off = 1; off < 256; off <<= 1) {
        int v = (t >= off) ? tmp[t - off] : 0;
        __syncthreads();
        tmp[t] += v;
        __syncthreads();
    }
    int excl = tmp[t] - s;                       // exclusive prefix within block
    if (base     < n) exsc[base]     = excl;
    if (base + 1 < n) exsc[base + 1] = excl + v0;
    if (base + 2 < n) exsc[base + 2] = excl + v0 + v1;
    if (base + 3 < n) exsc[base + 3] = excl + v0 + v1 + v2;
    if (t == 255) bsums[blockIdx.x] = tmp[255];  // block total
}

// ---- KC: single-block exclusive scan of block sums (in place) + n_triple_s ----
__global__ void kC_scan2(int* __restrict__ bsums, const int* __restrict__ exsc,
                         const int* __restrict__ n_atoms_arr, int* __restrict__ out_s,
                         int nb, int n_atom, int n_struct) {
    const int B = 256;
    __shared__ int sums[B];
    int t = threadIdx.x;
    int chunk = (nb + B - 1) / B;
    int lo = t * chunk; if (lo > nb) lo = nb;
    int hi = lo + chunk; if (hi > nb) hi = nb;
    int ssum = 0;
    for (int i = lo; i < hi; i++) ssum += bsums[i];
    sums[t] = ssum;
    __syncthreads();
    for (int off = 1; off < B; off <<= 1) {
        int v = (t >= off) ? sums[t - off] : 0;
        __syncthreads();
        sums[t] += v;
        __syncthreads();
    }
    int run = sums[t] - ssum;
    for (int i = lo; i < hi; i++) { int v = bsums[i]; bsums[i] = run; run += v; }
    int total = sums[B - 1];
    __syncthreads();
    if (t == 0) {
        int off = 0, prevA = 0;
        for (int s = 0; s < n_struct; s++) {
            off += n_atoms_arr[s];
            int A = (off >= n_atom) ? total : (exsc[off] + bsums[off >> 10]);
            out_s[s] = A - prevA;
            prevA = A;
        }
    }
}

// ---- KD: wave-per-atom triple enumeration + n_triple_ij (4 atoms / block) ----
// Nontemporal stores for the write-once outputs; ballots cached in registers
// so the n_triple_ij pass re-reads no len. Two consecutive triples per lane
// iteration as one 16B NT store (every tstart/base_row is even).
__global__ void kD_enum(const float* __restrict__ len, const int* __restrict__ wstart,
                        const int* __restrict__ wend, const int* __restrict__ exsc,
                        const int* __restrict__ bsums,
                        v4i* __restrict__ out4, int* __restrict__ out_ij,
                        int n_atom) {
    __shared__ int keptIds[4 * MAXD];
    int wave = threadIdx.x >> 6;
    int lane = threadIdx.x & 63;
    int a = blockIdx.x * 4 + wave;
    int* my = &keptIds[wave * MAXD];
    if (a >= n_atom) return;
    int s = wstart[a], e = wend[a];
    int d = 0;
    unsigned long long bal[4] = {0ull, 0ull, 0ull, 0ull};
    // order-preserving compaction of kept ORIGINAL bond ids into LDS
#pragma unroll
    for (int it = 0; it < 4; ++it) {             // static indices -> registers
        int base = s + it * 64;
        if (base < e) {
            int idx = base + lane;
            bool m = (idx < e) && (len[idx] <= CUTOFF);
            unsigned long long b = __ballot(m);
            bal[it] = b;
            int pos = d + __popcll(b & ((1ull << lane) - 1ull));
            if (m && pos < MAXD) my[pos] = idx;
            d += __popcll(b);
        }
    }
    for (int base = s + 256; base < e; base += 64) {   // cold path (d>256 never)
        int idx = base + lane;
        bool m = (idx < e) && (len[idx] <= CUTOFF);
        unsigned long long b = __ballot(m);
        int pos = d + __popcll(b & ((1ull << lane) - 1ull));
        if (m && pos < MAXD) my[pos] = idx;
        d += __popcll(b);
    }
    int dm1 = d - 1;
#pragma unroll
    for (int it = 0; it < 4; ++it) {
        int idx = s + it * 64 + lane;
        if (idx < e)
            __builtin_nontemporal_store(((bal[it] >> lane) & 1ull) ? dm1 : 0, &out_ij[idx]);
    }
    for (int base = s + 256; base < e; base += 64) {   // cold path
        int idx = base + lane;
        if (idx < e)
            __builtin_nontemporal_store((len[idx] <= CUTOFF) ? dm1 : 0, &out_ij[idx]);
    }
    if (d >= 2) {
        unsigned udm1 = (unsigned)dm1;
        unsigned nP = ((unsigned)(d * dm1)) >> 1;        // pairs of triples
        int b4 = (exsc[a] + bsums[a >> 10]) >> 1;        // tstart[a]/2, exact
        for (unsigned p = lane; p < nP; p += 64) {
            unsigned t0 = 2u * p;
            unsigned j  = t0 / udm1;                     // one div per PAIR
            unsigned kp = t0 - j * udm1;
            unsigned j1 = j, kp1 = kp + 1;
            if (kp1 == udm1) { j1++; kp1 = 0; }          // t0+1 rollover
            unsigned k0 = kp  + (kp  >= j  ? 1u : 0u);   // skip k == j
            unsigned k1 = kp1 + (kp1 >= j1 ? 1u : 0u);
            v4i q = (v4i){my[j], my[k0], my[j1], my[k1]};
            __builtin_nontemporal_store(q, &out4[b4 + p]);
        }
    }
}

// ================================ launch ================================
extern "C" void kernel_launch(void* const* d_in, const int* in_sizes, int n_in,
                              void* d_out, int out_size, void* d_ws, size_t ws_size,
                              hipStream_t stream) {
    const int*   bond_src    = (const int*)d_in[0];
    const float* bond_len    = (const float*)d_in[1];
    const int*   n_atoms_arr = (const int*)d_in[2];
    int n_bond   = in_sizes[0];
    int n_struct = in_sizes[2];
    const int n_atom = NATOM_C;
    int T2 = out_size - n_bond - n_atom - n_struct;   // = 2*T

    int nblk_scan = (n_atom + 1023) / 1024;           // 98 (<= 256 required)

    // workspace (ints): wstart | wend | deg | exsc[n_atom] | bsums[nblk]
    int* ws     = (int*)d_ws;
    int* wstart = ws;
    int* wend   = ws + n_atom;
    int* deg    = ws + 2 * n_atom;
    int* exsc   = ws + 3 * n_atom;
    int* bsums  = exsc + n_atom;

    int*  out       = (int*)d_out;
    v4i*  out_pairs = (v4i*)out;           // [T/2] rows of 2 triples, 16B-aligned
    int*  out_ij    = out + T2;
    int*  out_i     = out_ij + n_bond;
    int*  out_s     = out_i + n_atom;

    k0_init      <<<(n_atom + 255) / 256, 256, 0, stream>>>(wstart, wend, deg, n_atom);
    kA_bounds_deg<<<(n_bond + 255) / 256, 256, 0, stream>>>(bond_src, bond_len, wstart, wend, deg, n_bond);
    kB_scan      <<<nblk_scan, 256, 0, stream>>>(deg, out_i, exsc, bsums, n_atom);
    kC_scan2     <<<1, 256, 0, stream>>>(bsums, exsc, n_atoms_arr, out_s, nblk_scan, n_atom, n_struct);
    kD_enum      <<<(n_atom + 3) / 4, 256, 0, stream>>>(bond_len, wstart, wend, exsc, bsums,
                                                        out_pairs, out_ij, n_atom);
}